// Round 3
// baseline (358.634 us; speedup 1.0000x reference)
//
#include <hip/hip_runtime.h>
#include <hip/hip_cooperative_groups.h>
#include <math.h>

namespace cg = cooperative_groups;

// Problem constants (fixed by setup_inputs): C=64 channels, HW=128*128, bins=256.
#define C_CH   64
#define HW     16384
#define BINS   256
#define SPLIT  8                 // blocks per channel
#define SEG    (HW / SPLIT)      // 2048 elements per block segment
#define NTHR   256
#define NBLK   (C_CH * SPLIT)    // 512 blocks = 2 blocks/CU, trivially co-resident

// ---- ws layout (32-bit cells; everything fully written before read -> no init) ----
#define WS_PMN   0               // 512 floats: per-block min of match*mask
#define WS_PMX   512             // 512 floats: per-block max
#define WS_PXMN  1024            // 8 floats: ch0 input*mask segment mins
#define WS_PXMX  1032            // 8 floats: ch0 input*mask segment maxs
#define WS_PMS   1040            // 8 floats: mask segment sums
#define WS_SSE   1048            // 512 floats: per-block SSE partials
#define WS_HIST8 2048            // 512*256 ints: per-block 256-bin sub-histograms

__device__ inline float4 ld4(const float* p) { return *(const float4*)p; }

__device__ inline int lbound(const float* a, float rank) {
    int lo = 0, hi = BINS;
    while (lo < hi) { int mid = (lo + hi) >> 1; if (a[mid] < rank) lo = mid + 1; else hi = mid; }
    return (lo > 255) ? 255 : lo;   // cannot trigger (a[255] = N >= rank); defensive
}

__device__ inline void scan256(int* h, int tid) {   // Hillis-Steele inclusive
    for (int off = 1; off < BINS; off <<= 1) {
        int v = h[tid] + ((tid >= off) ? h[tid - off] : 0);
        __syncthreads();
        h[tid] = v;
        __syncthreads();
    }
}

__device__ inline float blk_reduce(float v, float* red, int tid, bool is_min, bool is_max) {
    red[tid] = v; __syncthreads();
    for (int st = 128; st > 0; st >>= 1) {
        if (tid < st) {
            float a = red[tid], b = red[tid + st];
            red[tid] = is_min ? fminf(a, b) : (is_max ? fmaxf(a, b) : (a + b));
        }
        __syncthreads();
    }
    float r = red[0]; __syncthreads();
    return r;
}

__global__ __launch_bounds__(NTHR, 2) void fused(const float* __restrict__ input,
                                                 const float* __restrict__ match,
                                                 const float* __restrict__ mask,
                                                 float* ws, float* out) {
    cg::grid_group grid = cg::this_grid();
    const int b = blockIdx.x, c = b >> 3, s = b & (SPLIT - 1), tid = threadIdx.x;
    const int base = s * SEG;
    int* wsi = (int*)ws;

    __shared__ float red[NTHR];
    __shared__ int   ihist[BINS];
    __shared__ float scdf[BINS];
    __shared__ float sT[BINS];

    const float* m  = match + c * HW + base;
    const float* mk = mask + base;
    const float* x  = input + c * HW + base;

    // ================= phase 1: segment min/max of mm = match*mask =================
    {
        float mn = INFINITY, mx = -INFINITY;
        #pragma unroll
        for (int k = 0; k < 2; k++) {
            float4 mv = ld4(m + k * 1024 + 4 * tid);
            float4 kv = ld4(mk + k * 1024 + 4 * tid);
            float v0 = mv.x * kv.x, v1 = mv.y * kv.y, v2 = mv.z * kv.z, v3 = mv.w * kv.w;
            mn = fminf(mn, fminf(fminf(v0, v1), fminf(v2, v3)));
            mx = fmaxf(mx, fmaxf(fmaxf(v0, v1), fmaxf(v2, v3)));
        }
        mn = blk_reduce(mn, red, tid, true, false);
        mx = blk_reduce(mx, red, tid, false, true);
        if (tid == 0) { ws[WS_PMN + b] = mn; ws[WS_PMX + b] = mx; }

        if (c == 0) {   // ch0 of input*mask min/max + mask partial sum
            float xmn = INFINITY, xmx = -INFINITY, msum = 0.0f;
            #pragma unroll
            for (int k = 0; k < 2; k++) {
                float4 xv = ld4(x + k * 1024 + 4 * tid);
                float4 kv = ld4(mk + k * 1024 + 4 * tid);
                float v0 = xv.x * kv.x, v1 = xv.y * kv.y, v2 = xv.z * kv.z, v3 = xv.w * kv.w;
                xmn = fminf(xmn, fminf(fminf(v0, v1), fminf(v2, v3)));
                xmx = fmaxf(xmx, fmaxf(fmaxf(v0, v1), fmaxf(v2, v3)));
                msum += kv.x + kv.y + kv.z + kv.w;   // 0/1 values: exact
            }
            xmn = blk_reduce(xmn, red, tid, true, false);
            xmx = blk_reduce(xmx, red, tid, false, true);
            msum = blk_reduce(msum, red, tid, false, false);
            if (tid == 0) { ws[WS_PXMN + s] = xmn; ws[WS_PXMX + s] = xmx; ws[WS_PMS + s] = msum; }
        }
    }
    __threadfence();
    grid.sync();

    // ============ phase 2: channel min/max fold + per-block LDS sub-histogram ============
    {
        float mn = INFINITY, mx = -INFINITY;
        #pragma unroll
        for (int j = 0; j < SPLIT; j++) {
            mn = fminf(mn, ws[WS_PMN + c * SPLIT + j]);
            mx = fmaxf(mx, ws[WS_PMX + c * SPLIT + j]);
        }
        // torch.histc: w = (mx-mn)/bins; safe_w = w>0 ? w : 1   (/256 exact)
        float w  = (mx - mn) * (1.0f / 256.0f);
        float sw = (w > 0.0f) ? w : 1.0f;

        ihist[tid] = 0;
        __syncthreads();
        #pragma unroll
        for (int k = 0; k < 2; k++) {
            float4 mv = ld4(m + k * 1024 + 4 * tid);
            float4 kv = ld4(mk + k * 1024 + 4 * tid);
            float v[4] = { mv.x * kv.x, mv.y * kv.y, mv.z * kv.z, mv.w * kv.w };
            #pragma unroll
            for (int j = 0; j < 4; j++) {
                float bb = floorf((v[j] - mn) / sw);
                bb = fminf(fmaxf(bb, 0.0f), 255.0f);   // clip in float like the reference
                atomicAdd(&ihist[(int)bb], 1);
            }
        }
        __syncthreads();
        wsi[WS_HIST8 + b * BINS + tid] = ihist[tid];
    }
    __threadfence();
    grid.sync();

    // ==== phase 3: redundant per-block cdf scan (+ch0 scan for T LUT), then loss ====
    {
        // own-channel cdf
        int h = 0;
        #pragma unroll
        for (int j = 0; j < SPLIT; j++) h += wsi[WS_HIST8 + (c * SPLIT + j) * BINS + tid];
        ihist[tid] = h;
        __syncthreads();
        scan256(ihist, tid);
        scdf[tid] = (float)ihist[tid];   // ints <= 16384: exact in fp32
        __syncthreads();

        if (c != 0) {   // channel-0 cdf (needed for the T LUT)
            int h0 = 0;
            #pragma unroll
            for (int j = 0; j < SPLIT; j++) h0 += wsi[WS_HIST8 + j * BINS + tid];
            ihist[tid] = h0;
            __syncthreads();
            scan256(ihist, tid);
        }
        red[tid] = (float)ihist[tid];    // cdf0
        __syncthreads();

        // T[j] from channel-0 stats: idx = count(cdf0 < j+1) == lower_bound (monotone)
        float xmn = INFINITY, xmx = -INFINITY;
        #pragma unroll
        for (int j = 0; j < SPLIT; j++) {
            xmn = fminf(xmn, ws[WS_PXMN + j]);
            xmx = fmaxf(xmx, ws[WS_PXMX + j]);
        }
        float step = (xmx - xmn) * (1.0f / 256.0f);
        float rank = (float)(tid + 1);
        int idx = lbound(red, rank);
        float cp = (idx > 0) ? red[idx - 1] : 0.0f;
        float cc = red[idx];
        float ratio = fminf(fmaxf((rank - cp) / (1e-8f + cc), 0.0f), 1.0f);
        sT[tid] = xmn + (ratio + (float)idx) * step;
        __syncthreads();

        // loss: binary search once, then monotone marching pointer
        float rank0 = (float)(base + 4 * tid + 1);
        int lo = lbound(scdf, rank0);

        float acc = 0.0f;
        #pragma unroll
        for (int k = 0; k < 2; k++) {
            float4 xv = ld4(x + k * 1024 + 4 * tid);
            float4 kv = ld4(mk + k * 1024 + 4 * tid);
            float v[4] = { xv.x * kv.x, xv.y * kv.y, xv.z * kv.z, xv.w * kv.w };
            int n0 = base + k * 1024 + 4 * tid;
            #pragma unroll
            for (int j = 0; j < 4; j++) {
                float rnk = (float)(n0 + j + 1);
                while (scdf[lo] < rnk) lo++;   // scdf[255] = N bounds the march
                float d = sT[lo] - v[j];
                acc += d * d;
            }
        }
        acc = blk_reduce(acc, red, tid, false, false);
        if (tid == 0) ws[WS_SSE + b] = acc;
    }
    __threadfence();
    grid.sync();

    // ================= phase 4: block 0 folds partials, writes the scalar =================
    if (b == 0) {
        float v = ws[WS_SSE + tid] + ws[WS_SSE + NTHR + tid];
        float sse = blk_reduce(v, red, tid, false, false);
        if (tid == 0) {
            float msum = 0.0f;
            #pragma unroll
            for (int j = 0; j < SPLIT; j++) msum += ws[WS_PMS + j];
            double mean = (double)sse / (double)(C_CH * HW);
            out[0] = (float)(mean * (double)msum * (double)C_CH / (double)(C_CH * HW));
        }
    }
}

extern "C" void kernel_launch(void* const* d_in, const int* in_sizes, int n_in,
                              void* d_out, int out_size, void* d_ws, size_t ws_size,
                              hipStream_t stream) {
    const float* input = (const float*)d_in[0];
    const float* match = (const float*)d_in[1];
    const float* mask  = (const float*)d_in[2];
    float* ws          = (float*)d_ws;
    float* out         = (float*)d_out;

    void* args[] = { (void*)&input, (void*)&match, (void*)&mask, (void*)&ws, (void*)&out };
    hipLaunchCooperativeKernel((const void*)fused, dim3(NBLK), dim3(NTHR), args, 0, stream);
}

// Round 4
// 97.406 us; speedup vs baseline: 3.6818x; 3.6818x over previous
//
#include <hip/hip_runtime.h>
#include <math.h>

// Problem constants (fixed by setup_inputs): C=64 channels, HW=128*128, bins=256.
#define C_CH  64
#define HW    16384
#define BINS  256

// ---- ws layout (32-bit cells; everything written before read -> no memset) ----
#define WS_CDF   0                    // 64*256 floats: per-channel inclusive cdf
#define WS_XMN   (C_CH * BINS)        // ch0 input*mask min
#define WS_XMX   (WS_XMN + 1)        // ch0 input*mask max
#define WS_MSUM  (WS_XMN + 2)        // mask sum
#define WS_SSE   (WS_XMN + 3)        // float SSE accumulator (zeroed by K1)
#define WS_CNT   (WS_XMN + 4)        // int ticket counter   (zeroed by K1)

__device__ inline float4 ld4(const float* p) { return *(const float4*)p; }

__device__ inline int lbound(const float* a, float rank) {
    int lo = 0, hi = BINS;
    while (lo < hi) { int mid = (lo + hi) >> 1; if (a[mid] < rank) lo = mid + 1; else hi = mid; }
    return (lo > 255) ? 255 : lo;   // cannot trigger (a[255]=N>=rank); defensive
}

// K1: blocks 0..63 = one channel each: min/max of mm=match*mask, 256-bin LDS
// histogram (zero-bin counted separately to avoid serialized same-address
// atomics from the ~30% masked-out zeros), inclusive scan -> cdf.
// Block 64: ch0 input*mask min/max + mask sum + zero sse/ticket.
__global__ __launch_bounds__(1024) void k1_hist(const float* __restrict__ input,
                                                const float* __restrict__ match,
                                                const float* __restrict__ mask,
                                                float* __restrict__ ws) {
    const int b = blockIdx.x, tid = threadIdx.x;
    __shared__ float red[1024];
    __shared__ int hist[BINS];

    if (b < C_CH) {
        const float* m = match + b * HW;

        // pass 1: min/max
        float mn = INFINITY, mx = -INFINITY;
        #pragma unroll
        for (int k = 0; k < 4; k++) {
            float4 mv = ld4(m + k * 4096 + 4 * tid);
            float4 kv = ld4(mask + k * 4096 + 4 * tid);
            float v0 = mv.x * kv.x, v1 = mv.y * kv.y, v2 = mv.z * kv.z, v3 = mv.w * kv.w;
            mn = fminf(mn, fminf(fminf(v0, v1), fminf(v2, v3)));
            mx = fmaxf(mx, fmaxf(fmaxf(v0, v1), fmaxf(v2, v3)));
        }
        red[tid] = mn; __syncthreads();
        for (int st = 512; st > 0; st >>= 1) { if (tid < st) red[tid] = fminf(red[tid], red[tid + st]); __syncthreads(); }
        mn = red[0]; __syncthreads();
        red[tid] = mx; __syncthreads();
        for (int st = 512; st > 0; st >>= 1) { if (tid < st) red[tid] = fmaxf(red[tid], red[tid + st]); __syncthreads(); }
        mx = red[0]; __syncthreads();

        // torch.histc: w = (mx-mn)/bins; safe_w = w>0 ? w : 1   (/256 exact)
        float w  = (mx - mn) * (1.0f / 256.0f);
        float sw = (w > 0.0f) ? w : 1.0f;

        if (tid < BINS) hist[tid] = 0;
        __syncthreads();

        // pass 2: histogram; exact-zero values counted locally (same bin for +-0)
        int zc = 0;
        #pragma unroll
        for (int k = 0; k < 4; k++) {
            float4 mv = ld4(m + k * 4096 + 4 * tid);
            float4 kv = ld4(mask + k * 4096 + 4 * tid);
            float v[4] = { mv.x * kv.x, mv.y * kv.y, mv.z * kv.z, mv.w * kv.w };
            #pragma unroll
            for (int j = 0; j < 4; j++) {
                if (v[j] == 0.0f) { zc++; }
                else {
                    float bb = floorf((v[j] - mn) / sw);
                    bb = fminf(fmaxf(bb, 0.0f), 255.0f);   // clip in float like the ref
                    atomicAdd(&hist[(int)bb], 1);
                }
            }
        }
        red[tid] = (float)zc; __syncthreads();
        for (int st = 512; st > 0; st >>= 1) { if (tid < st) red[tid] += red[tid + st]; __syncthreads(); }
        if (tid == 0) {
            float bb = floorf((0.0f - mn) / sw);           // bin of v==0 (matches per-elem calc)
            bb = fminf(fmaxf(bb, 0.0f), 255.0f);
            hist[(int)bb] += (int)red[0];
        }
        __syncthreads();

        // Hillis-Steele inclusive scan over 256 bins
        for (int off = 1; off < BINS; off <<= 1) {
            int v = 0;
            if (tid < BINS) v = hist[tid] + ((tid >= off) ? hist[tid - off] : 0);
            __syncthreads();
            if (tid < BINS) hist[tid] = v;
            __syncthreads();
        }
        if (tid < BINS) ws[WS_CDF + b * BINS + tid] = (float)hist[tid];  // ints <= 16384: exact
    } else {
        // block 64: ch0 x=input*mask min/max, mask sum, zero accumulators
        float xmn = INFINITY, xmx = -INFINITY, msum = 0.0f;
        #pragma unroll
        for (int k = 0; k < 4; k++) {
            float4 xv = ld4(input + k * 4096 + 4 * tid);
            float4 kv = ld4(mask + k * 4096 + 4 * tid);
            float v0 = xv.x * kv.x, v1 = xv.y * kv.y, v2 = xv.z * kv.z, v3 = xv.w * kv.w;
            xmn = fminf(xmn, fminf(fminf(v0, v1), fminf(v2, v3)));
            xmx = fmaxf(xmx, fmaxf(fmaxf(v0, v1), fmaxf(v2, v3)));
            msum += kv.x + kv.y + kv.z + kv.w;   // 0/1 values: exact
        }
        red[tid] = xmn; __syncthreads();
        for (int st = 512; st > 0; st >>= 1) { if (tid < st) red[tid] = fminf(red[tid], red[tid + st]); __syncthreads(); }
        xmn = red[0]; __syncthreads();
        red[tid] = xmx; __syncthreads();
        for (int st = 512; st > 0; st >>= 1) { if (tid < st) red[tid] = fmaxf(red[tid], red[tid + st]); __syncthreads(); }
        xmx = red[0]; __syncthreads();
        red[tid] = msum; __syncthreads();
        for (int st = 512; st > 0; st >>= 1) { if (tid < st) red[tid] += red[tid + st]; __syncthreads(); }
        if (tid == 0) {
            ws[WS_XMN] = xmn;
            ws[WS_XMX] = xmx;
            ws[WS_MSUM] = red[0];
            ws[WS_SSE] = 0.0f;
            ((int*)ws)[WS_CNT] = 0;
        }
    }
}

// K2: 1024 blocks x 256 threads, each block = 1024 contiguous elements of one
// channel. Rebuilds the T LUT locally from cdf0 + ch0 stats, marching-pointer
// CDF inversion, block reduce -> atomicAdd(sse). Ticket finale writes out[0].
__global__ __launch_bounds__(256) void k2_loss(const float* __restrict__ input,
                                               const float* __restrict__ mask,
                                               float* __restrict__ ws,
                                               float* __restrict__ out) {
    const int c = blockIdx.x >> 4;
    const int base = (blockIdx.x & 15) * 1024;
    const int tid = threadIdx.x;

    __shared__ float scdf[BINS], sc0[BINS], sT[BINS], red[256];
    scdf[tid] = ws[WS_CDF + c * BINS + tid];
    sc0[tid]  = ws[WS_CDF + tid];
    __syncthreads();

    // T[j] from channel-0 stats: idx = count(cdf0 < j+1) == lower_bound (monotone)
    const float xmn = ws[WS_XMN], xmx = ws[WS_XMX];
    {
        float step = (xmx - xmn) * (1.0f / 256.0f);
        float rank = (float)(tid + 1);
        int idx = lbound(sc0, rank);
        float cp = (idx > 0) ? sc0[idx - 1] : 0.0f;
        float cc = sc0[idx];
        float ratio = fminf(fmaxf((rank - cp) / (1e-8f + cc), 0.0f), 1.0f);
        sT[tid] = xmn + (ratio + (float)idx) * step;
    }
    __syncthreads();

    const float* x  = input + c * HW + base;
    const float* mk = mask + base;
    float4 xv = ld4(x + 4 * tid);
    float4 kv = ld4(mk + 4 * tid);
    float v[4] = { xv.x * kv.x, xv.y * kv.y, xv.z * kv.z, xv.w * kv.w };

    float rank0 = (float)(base + 4 * tid + 1);
    int lo = lbound(scdf, rank0);               // binary search once...
    float acc = 0.0f;
    #pragma unroll
    for (int j = 0; j < 4; j++) {
        float rnk = rank0 + (float)j;
        while (scdf[lo] < rnk) lo++;            // ...then monotone march (scdf[255]=N bounds it)
        float d = sT[lo] - v[j];
        acc += d * d;
    }

    red[tid] = acc; __syncthreads();
    for (int st = 128; st > 0; st >>= 1) { if (tid < st) red[tid] += red[tid + st]; __syncthreads(); }

    if (tid == 0) {
        atomicAdd(&ws[WS_SSE], red[0]);
        __threadfence();
        int old = atomicAdd(&((int*)ws)[WS_CNT], 1);
        if (old == gridDim.x - 1) {             // last block: all sse adds visible
            float sse  = atomicAdd(&ws[WS_SSE], 0.0f);   // coherent read
            float msum = ws[WS_MSUM];
            double mean = (double)sse / (double)(C_CH * HW);
            out[0] = (float)(mean * (double)msum * (double)C_CH / (double)(C_CH * HW));
        }
    }
}

extern "C" void kernel_launch(void* const* d_in, const int* in_sizes, int n_in,
                              void* d_out, int out_size, void* d_ws, size_t ws_size,
                              hipStream_t stream) {
    const float* input = (const float*)d_in[0];
    const float* match = (const float*)d_in[1];
    const float* mask  = (const float*)d_in[2];
    float* ws          = (float*)d_ws;
    float* out         = (float*)d_out;

    k1_hist<<<C_CH + 1, 1024, 0, stream>>>(input, match, mask, ws);
    k2_loss<<<C_CH * 16, 256,  0, stream>>>(input, mask, ws, out);
}

// Round 5
// 77.920 us; speedup vs baseline: 4.6026x; 1.2501x over previous
//
#include <hip/hip_runtime.h>
#include <math.h>

// Problem constants (fixed by setup_inputs): C=64 channels, HW=128*128, bins=256.
#define C_CH  64
#define HW    16384
#define BINS  256

// ---- ws layout (32-bit cells; everything written before read -> no memset) ----
#define WS_CDF   0                    // 64*256 floats: per-channel inclusive cdf
#define WS_XMN   (C_CH * BINS)       // ch0 input*mask min
#define WS_XMX   (WS_XMN + 1)        // ch0 input*mask max
#define WS_MSUM  (WS_XMN + 2)        // mask sum
#define WS_SSE   (WS_XMN + 3)        // float SSE accumulator (zeroed by K1 blk 64)
#define WS_CNT   (WS_XMN + 4)        // int ticket counter   (zeroed by K1 blk 64)

__device__ inline float4 ld4(const float* p) { return *(const float4*)p; }

__device__ inline int lbound(const float* a, float rank) {
    int lo = 0, hi = BINS;
    while (lo < hi) { int mid = (lo + hi) >> 1; if (a[mid] < rank) lo = mid + 1; else hi = mid; }
    return (lo > 255) ? 255 : lo;   // cannot trigger (a[255]=N>=rank); defensive
}

// K1: blocks 0..63 = one channel each. Single global pass: load 16 elems/thread
// into registers, wave-shuffle min/max, LDS histogram from registers (exact
// zeros counted separately — ~30% of values are masked-out zeros that would
// serialize same-address LDS atomics), wave-0 shuffle scan -> cdf.
// Block 64: ch0 input*mask min/max + mask sum + zero sse/ticket cells.
// Only ~4 __syncthreads per block (vs ~40 in the tree-reduction version).
__global__ __launch_bounds__(1024, 4) void k1_hist(const float* __restrict__ input,
                                                   const float* __restrict__ match,
                                                   const float* __restrict__ mask,
                                                   float* __restrict__ ws) {
    const int b = blockIdx.x, tid = threadIdx.x;
    const int wave = tid >> 6, lane = tid & 63;
    __shared__ float wmin[16], wmax[16], wsum[16];
    __shared__ int hist[BINS];

    if (b < C_CH) {
        const float* m = match + b * HW;

        // single pass: load+mask into registers, track min/max
        float v[16];
        float mn = INFINITY, mx = -INFINITY;
        #pragma unroll
        for (int k = 0; k < 4; k++) {
            float4 mv = ld4(m + k * 4096 + 4 * tid);
            float4 kv = ld4(mask + k * 4096 + 4 * tid);
            v[4 * k + 0] = mv.x * kv.x; v[4 * k + 1] = mv.y * kv.y;
            v[4 * k + 2] = mv.z * kv.z; v[4 * k + 3] = mv.w * kv.w;
            #pragma unroll
            for (int j = 0; j < 4; j++) {
                mn = fminf(mn, v[4 * k + j]);
                mx = fmaxf(mx, v[4 * k + j]);
            }
        }
        // wave-level reduce (no barriers), then cross-wave via LDS (1 barrier)
        #pragma unroll
        for (int s = 32; s > 0; s >>= 1) {
            mn = fminf(mn, __shfl_xor(mn, s, 64));
            mx = fmaxf(mx, __shfl_xor(mx, s, 64));
        }
        if (lane == 0) { wmin[wave] = mn; wmax[wave] = mx; }
        if (tid < BINS) hist[tid] = 0;
        __syncthreads();
        mn = wmin[0]; mx = wmax[0];
        #pragma unroll
        for (int j = 1; j < 16; j++) { mn = fminf(mn, wmin[j]); mx = fmaxf(mx, wmax[j]); }

        // torch.histc: w = (mx-mn)/bins; safe_w = w>0 ? w : 1   (/256 exact)
        float w  = (mx - mn) * (1.0f / 256.0f);
        float sw = (w > 0.0f) ? w : 1.0f;

        // histogram from registers; exact zeros (incl -0) counted without atomics
        int zc = 0;
        #pragma unroll
        for (int j = 0; j < 16; j++) {
            if (v[j] == 0.0f) { zc++; }
            else {
                float bb = floorf((v[j] - mn) / sw);
                bb = fminf(fmaxf(bb, 0.0f), 255.0f);   // clip in float like the ref
                atomicAdd(&hist[(int)bb], 1);
            }
        }
        // reduce zero-count: wave shuffle + LDS fold
        #pragma unroll
        for (int s = 32; s > 0; s >>= 1) zc += __shfl_xor(zc, s, 64);
        if (lane == 0) wsum[wave] = (float)zc;
        __syncthreads();
        if (tid == 0) {
            int z = 0;
            #pragma unroll
            for (int j = 0; j < 16; j++) z += (int)wsum[j];
            float bb = floorf((0.0f - mn) / sw);       // bin of v==0 (same calc as per-elem)
            bb = fminf(fmaxf(bb, 0.0f), 255.0f);
            hist[(int)bb] += z;
        }
        __syncthreads();

        // wave 0: 256-bin inclusive scan, 4 bins/lane, shuffle prefix — no barriers
        if (wave == 0) {
            int h0 = hist[4 * lane], h1 = hist[4 * lane + 1];
            int h2 = hist[4 * lane + 2], h3 = hist[4 * lane + 3];
            int p1 = h0 + h1, p2 = p1 + h2, s4 = p2 + h3;
            int sc = s4;
            #pragma unroll
            for (int off = 1; off < 64; off <<= 1) {
                int t = __shfl_up(sc, off, 64);
                if (lane >= off) sc += t;
            }
            int e = sc - s4;   // exclusive prefix
            float4 o = make_float4((float)(e + h0), (float)(e + p1),
                                   (float)(e + p2), (float)(e + s4));  // ints<=16384: exact
            *(float4*)&ws[WS_CDF + b * BINS + 4 * lane] = o;
        }
    } else {
        // block 64: ch0 x=input*mask min/max, mask sum, zero accumulators
        float xmn = INFINITY, xmx = -INFINITY, msum = 0.0f;
        #pragma unroll
        for (int k = 0; k < 4; k++) {
            float4 xv = ld4(input + k * 4096 + 4 * tid);
            float4 kv = ld4(mask + k * 4096 + 4 * tid);
            float v0 = xv.x * kv.x, v1 = xv.y * kv.y, v2 = xv.z * kv.z, v3 = xv.w * kv.w;
            xmn = fminf(xmn, fminf(fminf(v0, v1), fminf(v2, v3)));
            xmx = fmaxf(xmx, fmaxf(fmaxf(v0, v1), fmaxf(v2, v3)));
            msum += kv.x + kv.y + kv.z + kv.w;   // 0/1 values: exact
        }
        #pragma unroll
        for (int s = 32; s > 0; s >>= 1) {
            xmn = fminf(xmn, __shfl_xor(xmn, s, 64));
            xmx = fmaxf(xmx, __shfl_xor(xmx, s, 64));
            msum += __shfl_xor(msum, s, 64);
        }
        if (lane == 0) { wmin[wave] = xmn; wmax[wave] = xmx; wsum[wave] = msum; }
        __syncthreads();
        if (tid == 0) {
            #pragma unroll
            for (int j = 1; j < 16; j++) {
                xmn = fminf(xmn, wmin[j]);
                xmx = fmaxf(xmx, wmax[j]);
            }
            float ms = 0.0f;
            #pragma unroll
            for (int j = 0; j < 16; j++) ms += wsum[j];
            ws[WS_XMN] = xmn;
            ws[WS_XMX] = xmx;
            ws[WS_MSUM] = ms;
            ws[WS_SSE] = 0.0f;
            ((int*)ws)[WS_CNT] = 0;
        }
    }
}

// K2: 256 blocks x 256 threads, each block = 4096 contiguous elements of one
// channel (4 blocks/channel). Rebuilds the T LUT locally from cdf0 + ch0 stats,
// marching-pointer CDF inversion, block reduce -> atomicAdd(sse) (256 total
// same-address atomics, not 1024). Ticket finale writes out[0].
__global__ __launch_bounds__(256) void k2_loss(const float* __restrict__ input,
                                               const float* __restrict__ mask,
                                               float* __restrict__ ws,
                                               float* __restrict__ out) {
    const int c = blockIdx.x >> 2;
    const int base = (blockIdx.x & 3) * 4096;
    const int tid = threadIdx.x;
    const int wave = tid >> 6, lane = tid & 63;

    __shared__ float scdf[BINS], sc0[BINS], sT[BINS], red[4];
    scdf[tid] = ws[WS_CDF + c * BINS + tid];
    sc0[tid]  = ws[WS_CDF + tid];
    __syncthreads();

    // T[j] from channel-0 stats: idx = count(cdf0 < j+1) == lower_bound (monotone)
    {
        const float xmn = ws[WS_XMN], xmx = ws[WS_XMX];
        float step = (xmx - xmn) * (1.0f / 256.0f);
        float rank = (float)(tid + 1);
        int idx = lbound(sc0, rank);
        float cp = (idx > 0) ? sc0[idx - 1] : 0.0f;
        float cc = sc0[idx];
        float ratio = fminf(fmaxf((rank - cp) / (1e-8f + cc), 0.0f), 1.0f);
        sT[tid] = xmn + (ratio + (float)idx) * step;
    }
    __syncthreads();

    const float* x  = input + c * HW + base;
    const float* mk = mask + base;

    float acc = 0.0f;
    // first rank of this thread's first chunk: binary search; then monotone march
    int lo = lbound(scdf, (float)(base + 4 * tid + 1));
    #pragma unroll
    for (int k = 0; k < 4; k++) {
        float4 xv = ld4(x + k * 1024 + 4 * tid);
        float4 kv = ld4(mk + k * 1024 + 4 * tid);
        float v[4] = { xv.x * kv.x, xv.y * kv.y, xv.z * kv.z, xv.w * kv.w };
        float rank0 = (float)(base + k * 1024 + 4 * tid + 1);
        #pragma unroll
        for (int j = 0; j < 4; j++) {
            float rnk = rank0 + (float)j;
            while (scdf[lo] < rnk) lo++;   // scdf[255] = N bounds the march
            float d = sT[lo] - v[j];
            acc += d * d;
        }
    }

    // block reduce: wave shuffle + tiny LDS fold
    #pragma unroll
    for (int s = 32; s > 0; s >>= 1) acc += __shfl_xor(acc, s, 64);
    if (lane == 0) red[wave] = acc;
    __syncthreads();

    if (tid == 0) {
        float ssum = red[0] + red[1] + red[2] + red[3];
        atomicAdd(&ws[WS_SSE], ssum);
        __threadfence();
        int old = atomicAdd(&((int*)ws)[WS_CNT], 1);
        if (old == gridDim.x - 1) {             // last block: all sse adds visible
            float sse  = atomicAdd(&ws[WS_SSE], 0.0f);   // coherent read
            float msum = ws[WS_MSUM];
            double mean = (double)sse / (double)(C_CH * HW);
            out[0] = (float)(mean * (double)msum * (double)C_CH / (double)(C_CH * HW));
        }
    }
}

extern "C" void kernel_launch(void* const* d_in, const int* in_sizes, int n_in,
                              void* d_out, int out_size, void* d_ws, size_t ws_size,
                              hipStream_t stream) {
    const float* input = (const float*)d_in[0];
    const float* match = (const float*)d_in[1];
    const float* mask  = (const float*)d_in[2];
    float* ws          = (float*)d_ws;
    float* out         = (float*)d_out;

    k1_hist<<<C_CH + 1, 1024, 0, stream>>>(input, match, mask, ws);
    k2_loss<<<C_CH * 4, 256,  0, stream>>>(input, mask, ws, out);
}